// Round 5
// baseline (136.134 us; speedup 1.0000x reference)
//
#include <hip/hip_runtime.h>
#include <math.h>

// Problem dims (fixed by reference):
#define B_DIM 8
#define F_DIM 128
#define T_DIM 16384

#define SCAN_THREADS 512
#define CHUNK (T_DIM / SCAN_THREADS)   // 32 elements per thread
#define CHUNK4 (CHUNK / 4)             // 8 float4 per thread
#define LOG2_CHUNK 5

#define MV (F_DIM * T_DIM / 4)         // 524288 float4 per batch slice (= 2^19)
#define APPLY_THREADS 256

typedef float f32x4 __attribute__((ext_vector_type(4)));

// ---------------------------------------------------------------------------
// Kernel 1: parallel EMA scan along T for x0 = data[0], then
// Mepow = sign(m+eps)*|m+eps|^alpha (m+eps > 0 here since data >= 0, eps > 0).
// One block per frequency bin f. Linear recurrence m_t = a*m_{t-1} + s*x_t
// composes as affine (A,B): m_out = A*m_in + B.
// ---------------------------------------------------------------------------
__global__ __launch_bounds__(SCAN_THREADS) void pcen_scan_kernel(
    const float* __restrict__ x0,      // data[0] : [F, T]
    const float* __restrict__ p_alpha,
    const float* __restrict__ p_s,
    const float* __restrict__ p_eps,
    float* __restrict__ mepow)         // out: [F, T]
{
    const float alpha = p_alpha[0];
    const float s     = p_s[0];
    const float eps   = p_eps[0];
    const float a     = 1.0f - s;

    const int f    = blockIdx.x;
    const int tid  = threadIdx.x;
    const int lane = tid & 63;
    const int wave = tid >> 6;

    const f32x4* xrow = (const f32x4*)(x0 + (size_t)f * T_DIM);
    f32x4*       mrow = (f32x4*)(mepow + (size_t)f * T_DIM);

    const int vbase = tid * CHUNK4;

    // ---- Phase A: local recurrence with zero init; keep local m values in regs
    f32x4 y[CHUNK4];
    float m = 0.0f;
#pragma unroll
    for (int j = 0; j < CHUNK4; ++j) {
        f32x4 x = xrow[vbase + j];
        m = fmaf(a, m, s * x.x); x.x = m;
        m = fmaf(a, m, s * x.y); x.y = m;
        m = fmaf(a, m, s * x.z); x.z = m;
        m = fmaf(a, m, s * x.w); x.w = m;
        y[j] = x;
    }

    // Transfer function of this chunk: A = a^CHUNK (by squaring), B = final local m
    float A = a;
#pragma unroll
    for (int i = 0; i < LOG2_CHUNK; ++i) A = A * A;
    float B = m;

    // ---- Inclusive affine scan across the 64 lanes of the wave (Hillis-Steele)
#pragma unroll
    for (int d = 1; d < 64; d <<= 1) {
        float Ap = __shfl_up(A, d);
        float Bp = __shfl_up(B, d);
        if (lane >= d) {
            B = fmaf(A, Bp, B);   // compose: prev segment first, then mine
            A = A * Ap;
        }
    }

    // ---- Cross-wave combine via LDS (8 waves)
    __shared__ float wA[SCAN_THREADS / 64];
    __shared__ float wB[SCAN_THREADS / 64];
    if (lane == 63) { wA[wave] = A; wB[wave] = B; }
    __syncthreads();

    // exclusive scan within wave (state entering this thread's chunk, ignoring prior waves)
    float Ae = __shfl_up(A, 1);
    float Be = __shfl_up(B, 1);
    if (lane == 0) { Ae = 1.0f; Be = 0.0f; }

    // carry from all preceding waves applied to initial state 0
    float cB = 0.0f;
    for (int w = 0; w < wave; ++w) cB = fmaf(wA[w], cB, wB[w]);

    // true state entering this thread's chunk
    const float m_in = fmaf(Ae, cB, Be);

    // ---- Phase C: fixup m_k = y_k + a^(k+1)*m_in, then Mepow, store.
    // |mad|^alpha via hardware v_log_f32/v_exp_f32 (mad > 0 here; copysign kept
    // for exact sign semantics; log2(0) = -inf -> exp2 -> 0, still correct).
    float ap = a;
#pragma unroll
    for (int j = 0; j < CHUNK4; ++j) {
        f32x4 yv = y[j];
        f32x4 o;
        {
            float mv = fmaf(ap, m_in, yv.x); ap *= a;
            float mad = mv + eps;
            o.x = copysignf(__builtin_amdgcn_exp2f(alpha * __builtin_amdgcn_logf(fabsf(mad))), mad);
        }
        {
            float mv = fmaf(ap, m_in, yv.y); ap *= a;
            float mad = mv + eps;
            o.y = copysignf(__builtin_amdgcn_exp2f(alpha * __builtin_amdgcn_logf(fabsf(mad))), mad);
        }
        {
            float mv = fmaf(ap, m_in, yv.z); ap *= a;
            float mad = mv + eps;
            o.z = copysignf(__builtin_amdgcn_exp2f(alpha * __builtin_amdgcn_logf(fabsf(mad))), mad);
        }
        {
            float mv = fmaf(ap, m_in, yv.w); ap *= a;
            float mad = mv + eps;
            o.w = copysignf(__builtin_amdgcn_exp2f(alpha * __builtin_amdgcn_logf(fabsf(mad))), mad);
        }
        mrow[vbase + j] = o;
    }
}

// ---------------------------------------------------------------------------
// Kernel 2: elementwise PCEN apply. Each thread owns one (f,t) float4 position
// across all 8 batches -> Mepow loaded exactly once per position; reciprocal
// hoisted so the per-batch work is FMA + sqrt (r=0.5 fast path) instead of div.
// data/out are streaming (touched once) -> nontemporal to keep L2/L3 clean
// for the mepow re-reads.
// out = pow(data/Mepow + delta, |r|) - pow(delta, |r|)
// ---------------------------------------------------------------------------
__global__ __launch_bounds__(APPLY_THREADS) void pcen_apply_kernel(
    const float* __restrict__ data,    // [B, F, T]
    const float* __restrict__ mepow,   // [F, T]
    const float* __restrict__ p_r,
    const float* __restrict__ p_delta,
    float* __restrict__ out)           // [B, F, T]
{
    const float r_abs = fabsf(p_r[0]);
    const float delta = p_delta[0];

    const int v = blockIdx.x * APPLY_THREADS + threadIdx.x;   // < MV

    const f32x4* __restrict__ d4 = (const f32x4*)data + v;
    const f32x4* __restrict__ m4 = (const f32x4*)mepow + v;
    f32x4* __restrict__       o4 = (f32x4*)out + v;

    const f32x4 mp = *m4;
    f32x4 rc;
    rc.x = 1.0f / mp.x;
    rc.y = 1.0f / mp.y;
    rc.z = 1.0f / mp.z;
    rc.w = 1.0f / mp.w;

    if (r_abs == 0.5f) {
        const float dpr = sqrtf(delta);
#pragma unroll
        for (int b = 0; b < B_DIM; ++b) {
            f32x4 x = __builtin_nontemporal_load(d4 + b * MV);
            f32x4 o;
            o.x = sqrtf(fmaf(x.x, rc.x, delta)) - dpr;
            o.y = sqrtf(fmaf(x.y, rc.y, delta)) - dpr;
            o.z = sqrtf(fmaf(x.z, rc.z, delta)) - dpr;
            o.w = sqrtf(fmaf(x.w, rc.w, delta)) - dpr;
            __builtin_nontemporal_store(o, o4 + b * MV);
        }
    } else {
        const float dpr = powf(delta, r_abs);
#pragma unroll
        for (int b = 0; b < B_DIM; ++b) {
            f32x4 x = __builtin_nontemporal_load(d4 + b * MV);
            f32x4 o;
            o.x = powf(fmaf(x.x, rc.x, delta), r_abs) - dpr;
            o.y = powf(fmaf(x.y, rc.y, delta), r_abs) - dpr;
            o.z = powf(fmaf(x.z, rc.z, delta), r_abs) - dpr;
            o.w = powf(fmaf(x.w, rc.w, delta), r_abs) - dpr;
            __builtin_nontemporal_store(o, o4 + b * MV);
        }
    }
}

// ---------------------------------------------------------------------------
extern "C" void kernel_launch(void* const* d_in, const int* in_sizes, int n_in,
                              void* d_out, int out_size, void* d_ws, size_t ws_size,
                              hipStream_t stream) {
    const float* data    = (const float*)d_in[0];
    const float* p_alpha = (const float*)d_in[1];
    const float* p_r     = (const float*)d_in[2];
    const float* p_delta = (const float*)d_in[3];
    const float* p_s     = (const float*)d_in[4];
    const float* p_eps   = (const float*)d_in[5];
    float* out = (float*)d_out;

    // Workspace: Mepow [F, T] = 128*16384*4 B = 8 MiB
    float* mepow = (float*)d_ws;

    pcen_scan_kernel<<<F_DIM, SCAN_THREADS, 0, stream>>>(
        data, p_alpha, p_s, p_eps, mepow);

    pcen_apply_kernel<<<MV / APPLY_THREADS, APPLY_THREADS, 0, stream>>>(
        data, mepow, p_r, p_delta, out);
}